// Round 1
// baseline (152.021 us; speedup 1.0000x reference)
//
#include <hip/hip_runtime.h>

typedef __attribute__((ext_vector_type(8))) short s16x8;
typedef __attribute__((ext_vector_type(4))) float f32x4;
typedef unsigned short u16;

#define DEV __device__ __forceinline__

DEV u16 f2bf(float f) {
    unsigned u = __builtin_bit_cast(unsigned, f);
    unsigned r = u + 0x7fffu + ((u >> 16) & 1u);
    return (u16)(r >> 16);
}

DEV void gload_lds16(const void* g, void* l) {
    __builtin_amdgcn_global_load_lds(
        (const __attribute__((address_space(1))) unsigned int*)g,
        (__attribute__((address_space(3))) unsigned int*)l, 16, 0, 0);
}

DEV f32x4 mfma16(s16x8 a, s16x8 b, f32x4 c) {
    return __builtin_amdgcn_mfma_f32_16x16x32_bf16(a, b, c, 0, 0, 0);
}

// ---------------- LayerNorm: f32 in -> bf16 out, one block per row ----------------
__global__ __launch_bounds__(256) void ln_kernel(const float* __restrict__ x,
                                                 const float* __restrict__ g,
                                                 const float* __restrict__ b,
                                                 u16* __restrict__ xn) {
    const int row = blockIdx.x, t = threadIdx.x;
    const float4 v = *(const float4*)(x + (size_t)row * 1024 + t * 4);
    float s1 = v.x + v.y + v.z + v.w;
    float s2 = v.x * v.x + v.y * v.y + v.z * v.z + v.w * v.w;
#pragma unroll
    for (int d = 1; d < 64; d <<= 1) {
        s1 += __shfl_xor(s1, d);
        s2 += __shfl_xor(s2, d);
    }
    __shared__ float red[8];
    if ((t & 63) == 0) { red[(t >> 6) * 2] = s1; red[(t >> 6) * 2 + 1] = s2; }
    __syncthreads();
    s1 = red[0] + red[2] + red[4] + red[6];
    s2 = red[1] + red[3] + red[5] + red[7];
    const float mu = s1 * (1.0f / 1024.0f);
    const float var = s2 * (1.0f / 1024.0f) - mu * mu;
    const float rs = rsqrtf(var + 1e-5f);
    const float4 gv = *(const float4*)(g + t * 4);
    const float4 bv = *(const float4*)(b + t * 4);
    ushort4 o;
    o.x = f2bf((v.x - mu) * rs * gv.x + bv.x);
    o.y = f2bf((v.y - mu) * rs * gv.y + bv.y);
    o.z = f2bf((v.z - mu) * rs * gv.z + bv.z);
    o.w = f2bf((v.w - mu) * rs * gv.w + bv.w);
    *(ushort4*)(xn + (size_t)row * 1024 + t * 4) = o;
}

// -------- Weight transpose + cast: src f32 [1024 K][ld N] -> dst bf16 [N][1024] --------
__global__ __launch_bounds__(256) void transpose_w(const float* __restrict__ src,
                                                   u16* __restrict__ dst, int ld) {
    __shared__ float tile[64][68];
    const int t = threadIdx.x;
    const int n0 = blockIdx.x * 64, k0 = blockIdx.y * 64;
    const int kl = t >> 4, nl = (t & 15) * 4;
#pragma unroll
    for (int p = 0; p < 4; ++p) {
        float4 v = *(const float4*)(src + (size_t)(k0 + kl + p * 16) * ld + n0 + nl);
        tile[kl + p * 16][nl + 0] = v.x;
        tile[kl + p * 16][nl + 1] = v.y;
        tile[kl + p * 16][nl + 2] = v.z;
        tile[kl + p * 16][nl + 3] = v.w;
    }
    __syncthreads();
    const int nl2 = t >> 2, kc = (t & 3) * 16;
    __align__(16) u16 tmp[16];
#pragma unroll
    for (int j = 0; j < 16; ++j) tmp[j] = f2bf(tile[kc + j][nl2]);
    u16* d = dst + (size_t)(n0 + nl2) * 1024 + k0 + kc;
    ((uint4*)d)[0] = ((const uint4*)tmp)[0];
    ((uint4*)d)[1] = ((const uint4*)tmp)[1];
}

// -------- V transpose (bf16): per (b,h) [1024 j][64 d] -> [64 d][1024 j] --------
__global__ __launch_bounds__(256) void transpose_v(const u16* __restrict__ V,
                                                   u16* __restrict__ Vt) {
    __shared__ u16 tile[64][72];
    const int t = threadIdx.x;
    const int j0 = blockIdx.x * 64;
    const int bh = blockIdx.y;
    const u16* src = V + (size_t)bh * 65536;
    const int jl = t >> 4, dl = (t & 15) * 4;
#pragma unroll
    for (int p = 0; p < 4; ++p) {
        ushort4 v = *(const ushort4*)(src + (size_t)(j0 + jl + p * 16) * 64 + dl);
        *(ushort4*)&tile[jl + p * 16][dl] = v;
    }
    __syncthreads();
    const int dl2 = t >> 2, jc = (t & 3) * 16;
    __align__(16) u16 tmp[16];
#pragma unroll
    for (int j = 0; j < 16; ++j) tmp[j] = tile[jc + j][dl2];
    u16* d = Vt + (size_t)bh * 65536 + (size_t)dl2 * 1024 + j0 + jc;
    ((uint4*)d)[0] = ((const uint4*)tmp)[0];
    ((uint4*)d)[1] = ((const uint4*)tmp)[1];
}

// ---------------- GEMM C = A @ B^T, A[M][K] bf16, B[N][K] bf16 (K-major) ----------------
// 128x128 tile, BK=32, 4 waves (2x2), 16x16x32 MFMA, global_load_lds + XOR swizzle.
// EPI==0: scatter q/k/v (q scaled by 0.125). EPI==1: dual output + bias, f32.
template <int EPI>
__global__ __launch_bounds__(256) void gemm_bt(const u16* __restrict__ A,
                                               const u16* __restrict__ B,
                                               u16* __restrict__ Qb, u16* __restrict__ Kb,
                                               u16* __restrict__ Vb,
                                               const float* __restrict__ bx,
                                               const float* __restrict__ by,
                                               float* __restrict__ out, int K) {
    __shared__ __align__(16) u16 As[2][128 * 32];
    __shared__ __align__(16) u16 Bs[2][128 * 32];
    const int tid = threadIdx.x, lane = tid & 63;
    const int wave = tid >> 6, wm = wave >> 1, wn = wave & 1;
    const int m0 = blockIdx.y * 128, n0 = blockIdx.x * 128;
    const int lr = lane & 15, cg = lane >> 4;
    f32x4 acc[4][4] = {};

#define STAGE(bufi, k0)                                                            \
    do {                                                                           \
        _Pragma("unroll") for (int i = 0; i < 2; ++i) {                            \
            int idx = i * 256 + tid;                                               \
            int row = idx >> 2, p = idx & 3;                                       \
            int kk = (k0) + ((p ^ ((row >> 1) & 3)) << 3);                         \
            gload_lds16(A + (size_t)(m0 + row) * K + kk, &As[bufi][idx * 8]);      \
            gload_lds16(B + (size_t)(n0 + row) * K + kk, &Bs[bufi][idx * 8]);      \
        }                                                                          \
    } while (0)

    STAGE(0, 0);
    asm volatile("s_waitcnt vmcnt(0)" ::: "memory");
    __syncthreads();
    const int nk = K >> 5;
    for (int t = 0; t < nk; ++t) {
        const int buf = t & 1;
        if (t + 1 < nk) STAGE(buf ^ 1, (t + 1) << 5);
        s16x8 a[4], b[4];
#pragma unroll
        for (int f = 0; f < 4; ++f) {
            int r = wm * 64 + f * 16 + lr;
            a[f] = *(const s16x8*)&As[buf][r * 32 + ((cg ^ ((r >> 1) & 3)) << 3)];
            int r2 = wn * 64 + f * 16 + lr;
            b[f] = *(const s16x8*)&Bs[buf][r2 * 32 + ((cg ^ ((r2 >> 1) & 3)) << 3)];
        }
#pragma unroll
        for (int fm = 0; fm < 4; ++fm)
#pragma unroll
            for (int fn = 0; fn < 4; ++fn) acc[fm][fn] = mfma16(a[fm], b[fn], acc[fm][fn]);
        asm volatile("s_waitcnt vmcnt(0)" ::: "memory");
        __syncthreads();
    }
#undef STAGE

    const int colb = n0 + wn * 64 + lr;
    const int rowb = m0 + wm * 64 + cg * 4;
    if (EPI == 0) {
#pragma unroll
        for (int fn = 0; fn < 4; ++fn) {
            const int col = colb + fn * 16;
            const int which = col >> 10, hd = col & 1023;
            const int h = hd >> 6, dd = hd & 63;
            u16* dst = (which == 0) ? Qb : (which == 1) ? Kb : Vb;
            const float sc = (which == 0) ? 0.125f : 1.0f;
#pragma unroll
            for (int fm = 0; fm < 4; ++fm)
#pragma unroll
                for (int r = 0; r < 4; ++r) {
                    const int tk = rowb + fm * 16 + r;
                    const int bb = tk >> 10, ii = tk & 1023;
                    dst[(size_t)(((bb << 4) + h) * 1024 + ii) * 64 + dd] =
                        f2bf(acc[fm][fn][r] * sc);
                }
        }
    } else {
#pragma unroll
        for (int fn = 0; fn < 4; ++fn) {
            const int col = colb + fn * 16;
            float bias;
            float* ob;
            if (col < 1024) { bias = bx[col]; ob = out + col; }
            else { bias = by[col - 1024]; ob = out + 4194304 + (col - 1024); }
#pragma unroll
            for (int fm = 0; fm < 4; ++fm)
#pragma unroll
                for (int r = 0; r < 4; ++r) {
                    const int tk = rowb + fm * 16 + r;
                    ob[(size_t)tk * 1024] = acc[fm][fn][r] + bias;
                }
        }
    }
}

// ---------------- Flash attention: 64 (b,h) pairs, N=1024, D=64 ----------------
// Block: 4 waves, 64 q-rows (16 per wave). K/V double-buffered LDS (swizzled),
// online softmax via 16-lane shfl reductions, P via padded LDS.
__global__ __launch_bounds__(256) void attn_kernel(const u16* __restrict__ Q,
                                                   const u16* __restrict__ Kg,
                                                   const u16* __restrict__ Vt,
                                                   u16* __restrict__ xo) {
    __shared__ __align__(16) u16 Ks[2][64 * 64];
    __shared__ __align__(16) u16 Vs[2][64 * 64];
    __shared__ __align__(16) u16 Ps[4][16 * 72];
    const int tid = threadIdx.x, lane = tid & 63, w = tid >> 6;
    const int bh = blockIdx.x >> 4, qt = blockIdx.x & 15;
    const u16* Qh = Q + (size_t)bh * 65536;
    const u16* Kh = Kg + (size_t)bh * 65536;
    const u16* Vh = Vt + (size_t)bh * 65536;
    const int lr = lane & 15, cg = lane >> 4;
    const int q0 = qt * 64 + w * 16;

    s16x8 qf[2];
#pragma unroll
    for (int ks = 0; ks < 2; ++ks)
        qf[ks] = *(const s16x8*)(Qh + (size_t)(q0 + lr) * 64 + ks * 32 + cg * 8);

    f32x4 o[4] = {};
    float mrow[4] = {-1e30f, -1e30f, -1e30f, -1e30f};
    float lrow[4] = {0.f, 0.f, 0.f, 0.f};

#define STAGEKV(bufi, kv0)                                                               \
    do {                                                                                 \
        _Pragma("unroll") for (int i = 0; i < 2; ++i) {                                  \
            int idx = i * 256 + tid;                                                     \
            int row = idx >> 3, p = idx & 7;                                             \
            gload_lds16(Kh + (size_t)((kv0) + row) * 64 + ((p ^ (row & 7)) << 3),        \
                        &Ks[bufi][idx * 8]);                                             \
            gload_lds16(Vh + (size_t)row * 1024 + (kv0) + ((p ^ (row & 7)) << 3),        \
                        &Vs[bufi][idx * 8]);                                             \
        }                                                                                \
    } while (0)

    STAGEKV(0, 0);
    asm volatile("s_waitcnt vmcnt(0)" ::: "memory");
    __syncthreads();

    for (int t = 0; t < 16; ++t) {
        const int buf = t & 1;
        if (t < 15) STAGEKV(buf ^ 1, (t + 1) * 64);
        f32x4 s[4] = {};
#pragma unroll
        for (int ks = 0; ks < 2; ++ks) {
#pragma unroll
            for (int fn = 0; fn < 4; ++fn) {
                const int r = fn * 16 + lr;
                const int c = cg + ks * 4;
                s16x8 kf = *(const s16x8*)&Ks[buf][r * 64 + ((c ^ (r & 7)) << 3)];
                s[fn] = mfma16(qf[ks], kf, s[fn]);
            }
        }
        float corr[4];
#pragma unroll
        for (int r = 0; r < 4; ++r) {
            float mx = fmaxf(fmaxf(s[0][r], s[1][r]), fmaxf(s[2][r], s[3][r]));
#pragma unroll
            for (int d = 1; d < 16; d <<= 1) mx = fmaxf(mx, __shfl_xor(mx, d));
            const float nm = fmaxf(mrow[r], mx);
            corr[r] = __expf(mrow[r] - nm);
            mrow[r] = nm;
        }
        float rsum[4] = {0.f, 0.f, 0.f, 0.f};
#pragma unroll
        for (int fn = 0; fn < 4; ++fn)
#pragma unroll
            for (int r = 0; r < 4; ++r) {
                const float p = __expf(s[fn][r] - mrow[r]);
                rsum[r] += p;
                Ps[w][(4 * cg + r) * 72 + fn * 16 + lr] = f2bf(p);
            }
#pragma unroll
        for (int r = 0; r < 4; ++r) {
            float rs = rsum[r];
#pragma unroll
            for (int d = 1; d < 16; d <<= 1) rs += __shfl_xor(rs, d);
            lrow[r] = lrow[r] * corr[r] + rs;
#pragma unroll
            for (int fd = 0; fd < 4; ++fd) o[fd][r] *= corr[r];
        }
#pragma unroll
        for (int ks = 0; ks < 2; ++ks) {
            s16x8 pf = *(const s16x8*)&Ps[w][lr * 72 + ks * 32 + cg * 8];
#pragma unroll
            for (int fd = 0; fd < 4; ++fd) {
                const int rr = fd * 16 + lr;
                const int c = cg + ks * 4;
                s16x8 vf = *(const s16x8*)&Vs[buf][rr * 64 + ((c ^ (rr & 7)) << 3)];
                o[fd] = mfma16(pf, vf, o[fd]);
            }
        }
        asm volatile("s_waitcnt vmcnt(0)" ::: "memory");
        __syncthreads();
    }
#undef STAGEKV
    const int b = bh >> 4, h = bh & 15;
#pragma unroll
    for (int r = 0; r < 4; ++r) {
        const float inv = 1.0f / lrow[r];
        const int i = q0 + 4 * cg + r;
#pragma unroll
        for (int fd = 0; fd < 4; ++fd)
            xo[(size_t)(b * 1024 + i) * 1024 + h * 64 + fd * 16 + lr] =
                f2bf(o[fd][r] * inv);
    }
}

extern "C" void kernel_launch(void* const* d_in, const int* in_sizes, int n_in,
                              void* d_out, int out_size, void* d_ws, size_t ws_size,
                              hipStream_t stream) {
    const float* x = (const float*)d_in[0];
    const float* gx = (const float*)d_in[2];
    const float* bxv = (const float*)d_in[3];
    const float* Wqkv = (const float*)d_in[6];
    const float* Woutx = (const float*)d_in[8];
    const float* boutx = (const float*)d_in[9];
    const float* Wouty = (const float*)d_in[10];
    const float* bouty = (const float*)d_in[11];
    float* out = (float*)d_out;

    u16* ws = (u16*)d_ws;
    u16* xn = ws;                           // 4096*1024
    u16* wqkv_t = xn + 4096 * 1024;         // 3072*1024
    u16* wout_t = wqkv_t + 3072 * 1024;     // 2048*1024
    u16* Qb = wout_t + 2048 * 1024;         // 64*1024*64
    u16* Kb = Qb + 64 * 1024 * 64;
    u16* Vb = Kb + 64 * 1024 * 64;
    u16* Vtb = Vb + 64 * 1024 * 64;
    u16* xob = Vtb + 64 * 1024 * 64;        // 4096*1024

    ln_kernel<<<4096, 256, 0, stream>>>(x, gx, bxv, xn);
    transpose_w<<<dim3(48, 16), 256, 0, stream>>>(Wqkv, wqkv_t, 3072);
    transpose_w<<<dim3(16, 16), 256, 0, stream>>>(Woutx, wout_t, 1024);
    transpose_w<<<dim3(16, 16), 256, 0, stream>>>(Wouty, wout_t + 1024 * 1024, 1024);
    gemm_bt<0><<<dim3(24, 32), 256, 0, stream>>>(xn, wqkv_t, Qb, Kb, Vb, nullptr,
                                                 nullptr, nullptr, 1024);
    transpose_v<<<dim3(16, 64), 256, 0, stream>>>(Vb, Vtb);
    attn_kernel<<<1024, 256, 0, stream>>>(Qb, Kb, Vtb, xob);
    gemm_bt<1><<<dim3(16, 32), 256, 0, stream>>>(xob, wout_t, nullptr, nullptr, nullptr,
                                                 boutx, bouty, out, 1024);
}

// Round 2
// 135.382 us; speedup vs baseline: 1.1229x; 1.1229x over previous
//
#include <hip/hip_runtime.h>

typedef __attribute__((ext_vector_type(8))) short s16x8;
typedef __attribute__((ext_vector_type(4))) float f32x4;
typedef unsigned short u16;

#define DEV __device__ __forceinline__

DEV u16 f2bf(float f) {
    unsigned u = __builtin_bit_cast(unsigned, f);
    unsigned r = u + 0x7fffu + ((u >> 16) & 1u);
    return (u16)(r >> 16);
}

DEV float exp2a(float x) {
    float r;
    asm("v_exp_f32 %0, %1" : "=v"(r) : "v"(x));
    return r;
}

DEV unsigned cvtpk(float lo, float hi) {
    unsigned r;
    asm("v_cvt_pk_bf16_f32 %0, %1, %2" : "=v"(r) : "v"(lo), "v"(hi));
    return r;
}

DEV void gload_lds16(const void* g, void* l) {
    __builtin_amdgcn_global_load_lds(
        (const __attribute__((address_space(1))) unsigned int*)g,
        (__attribute__((address_space(3))) unsigned int*)l, 16, 0, 0);
}

DEV f32x4 mfma16(s16x8 a, s16x8 b, f32x4 c) {
    return __builtin_amdgcn_mfma_f32_16x16x32_bf16(a, b, c, 0, 0, 0);
}

// ---------------- LayerNorm: f32 in -> bf16 out, one block per row ----------------
__global__ __launch_bounds__(256) void ln_kernel(const float* __restrict__ x,
                                                 const float* __restrict__ g,
                                                 const float* __restrict__ b,
                                                 u16* __restrict__ xn) {
    const int row = blockIdx.x, t = threadIdx.x;
    const float4 v = *(const float4*)(x + (size_t)row * 1024 + t * 4);
    float s1 = v.x + v.y + v.z + v.w;
    float s2 = v.x * v.x + v.y * v.y + v.z * v.z + v.w * v.w;
#pragma unroll
    for (int d = 1; d < 64; d <<= 1) {
        s1 += __shfl_xor(s1, d);
        s2 += __shfl_xor(s2, d);
    }
    __shared__ float red[8];
    if ((t & 63) == 0) { red[(t >> 6) * 2] = s1; red[(t >> 6) * 2 + 1] = s2; }
    __syncthreads();
    s1 = red[0] + red[2] + red[4] + red[6];
    s2 = red[1] + red[3] + red[5] + red[7];
    const float mu = s1 * (1.0f / 1024.0f);
    const float var = s2 * (1.0f / 1024.0f) - mu * mu;
    const float rs = rsqrtf(var + 1e-5f);
    const float4 gv = *(const float4*)(g + t * 4);
    const float4 bv = *(const float4*)(b + t * 4);
    ushort4 o;
    o.x = f2bf((v.x - mu) * rs * gv.x + bv.x);
    o.y = f2bf((v.y - mu) * rs * gv.y + bv.y);
    o.z = f2bf((v.z - mu) * rs * gv.z + bv.z);
    o.w = f2bf((v.w - mu) * rs * gv.w + bv.w);
    *(ushort4*)(xn + (size_t)row * 1024 + t * 4) = o;
}

// -------- Weight transpose + cast: src f32 [1024 K][ld N] -> dst bf16 [N][1024] --------
__global__ __launch_bounds__(256) void transpose_w(const float* __restrict__ src,
                                                   u16* __restrict__ dst, int ld) {
    __shared__ float tile[64][68];
    const int t = threadIdx.x;
    const int n0 = blockIdx.x * 64, k0 = blockIdx.y * 64;
    const int kl = t >> 4, nl = (t & 15) * 4;
#pragma unroll
    for (int p = 0; p < 4; ++p) {
        float4 v = *(const float4*)(src + (size_t)(k0 + kl + p * 16) * ld + n0 + nl);
        tile[kl + p * 16][nl + 0] = v.x;
        tile[kl + p * 16][nl + 1] = v.y;
        tile[kl + p * 16][nl + 2] = v.z;
        tile[kl + p * 16][nl + 3] = v.w;
    }
    __syncthreads();
    const int nl2 = t >> 2, kc = (t & 3) * 16;
    __align__(16) u16 tmp[16];
#pragma unroll
    for (int j = 0; j < 16; ++j) tmp[j] = f2bf(tile[kc + j][nl2]);
    u16* d = dst + (size_t)(n0 + nl2) * 1024 + k0 + kc;
    ((uint4*)d)[0] = ((const uint4*)tmp)[0];
    ((uint4*)d)[1] = ((const uint4*)tmp)[1];
}

// -------- V transpose (bf16): per (b,h) [1024 j][64 d] -> [64 d][1024 j] --------
__global__ __launch_bounds__(256) void transpose_v(const u16* __restrict__ V,
                                                   u16* __restrict__ Vt) {
    __shared__ u16 tile[64][72];
    const int t = threadIdx.x;
    const int j0 = blockIdx.x * 64;
    const int bh = blockIdx.y;
    const u16* src = V + (size_t)bh * 65536;
    const int jl = t >> 4, dl = (t & 15) * 4;
#pragma unroll
    for (int p = 0; p < 4; ++p) {
        ushort4 v = *(const ushort4*)(src + (size_t)(j0 + jl + p * 16) * 64 + dl);
        *(ushort4*)&tile[jl + p * 16][dl] = v;
    }
    __syncthreads();
    const int dl2 = t >> 2, jc = (t & 3) * 16;
    __align__(16) u16 tmp[16];
#pragma unroll
    for (int j = 0; j < 16; ++j) tmp[j] = tile[jc + j][dl2];
    u16* d = Vt + (size_t)bh * 65536 + (size_t)dl2 * 1024 + j0 + jc;
    ((uint4*)d)[0] = ((const uint4*)tmp)[0];
    ((uint4*)d)[1] = ((const uint4*)tmp)[1];
}

// ---------------- GEMM C = A @ B^T, A[M][K] bf16, B[N][K] bf16 (K-major) ----------------
// 128x128 tile, BK=32, 4 waves (2x2), 16x16x32 MFMA, global_load_lds + XOR swizzle.
// EPI==0: scatter q/k/v (q scaled by SCALE*log2e). EPI==1: dual output + bias, f32.
template <int EPI>
__global__ __launch_bounds__(256) void gemm_bt(const u16* __restrict__ A,
                                               const u16* __restrict__ B,
                                               u16* __restrict__ Qb, u16* __restrict__ Kb,
                                               u16* __restrict__ Vb,
                                               const float* __restrict__ bx,
                                               const float* __restrict__ by,
                                               float* __restrict__ out, int K) {
    __shared__ __align__(16) u16 As[2][128 * 32];
    __shared__ __align__(16) u16 Bs[2][128 * 32];
    const int tid = threadIdx.x, lane = tid & 63;
    const int wave = tid >> 6, wm = wave >> 1, wn = wave & 1;
    const int m0 = blockIdx.y * 128, n0 = blockIdx.x * 128;
    const int lr = lane & 15, cg = lane >> 4;
    f32x4 acc[4][4] = {};

#define STAGE(bufi, k0)                                                            \
    do {                                                                           \
        _Pragma("unroll") for (int i = 0; i < 2; ++i) {                            \
            int idx = i * 256 + tid;                                               \
            int row = idx >> 2, p = idx & 3;                                       \
            int kk = (k0) + ((p ^ ((row >> 1) & 3)) << 3);                         \
            gload_lds16(A + (size_t)(m0 + row) * K + kk, &As[bufi][idx * 8]);      \
            gload_lds16(B + (size_t)(n0 + row) * K + kk, &Bs[bufi][idx * 8]);      \
        }                                                                          \
    } while (0)

    STAGE(0, 0);
    asm volatile("s_waitcnt vmcnt(0)" ::: "memory");
    __syncthreads();
    const int nk = K >> 5;
    for (int t = 0; t < nk; ++t) {
        const int buf = t & 1;
        if (t + 1 < nk) STAGE(buf ^ 1, (t + 1) << 5);
        s16x8 a[4], b[4];
#pragma unroll
        for (int f = 0; f < 4; ++f) {
            int r = wm * 64 + f * 16 + lr;
            a[f] = *(const s16x8*)&As[buf][r * 32 + ((cg ^ ((r >> 1) & 3)) << 3)];
            int r2 = wn * 64 + f * 16 + lr;
            b[f] = *(const s16x8*)&Bs[buf][r2 * 32 + ((cg ^ ((r2 >> 1) & 3)) << 3)];
        }
#pragma unroll
        for (int fm = 0; fm < 4; ++fm)
#pragma unroll
            for (int fn = 0; fn < 4; ++fn) acc[fm][fn] = mfma16(a[fm], b[fn], acc[fm][fn]);
        asm volatile("s_waitcnt vmcnt(0)" ::: "memory");
        __syncthreads();
    }
#undef STAGE

    const int colb = n0 + wn * 64 + lr;
    const int rowb = m0 + wm * 64 + cg * 4;
    if (EPI == 0) {
#pragma unroll
        for (int fn = 0; fn < 4; ++fn) {
            const int col = colb + fn * 16;
            const int which = col >> 10, hd = col & 1023;
            const int h = hd >> 6, dd = hd & 63;
            u16* dst = (which == 0) ? Qb : (which == 1) ? Kb : Vb;
            // Q pre-scaled by SCALE*log2(e) so softmax can use raw v_exp_f32 (exp2)
            const float sc = (which == 0) ? 0.18033688011112042f : 1.0f;
#pragma unroll
            for (int fm = 0; fm < 4; ++fm)
#pragma unroll
                for (int r = 0; r < 4; ++r) {
                    const int tk = rowb + fm * 16 + r;
                    const int bb = tk >> 10, ii = tk & 1023;
                    dst[(size_t)(((bb << 4) + h) * 1024 + ii) * 64 + dd] =
                        f2bf(acc[fm][fn][r] * sc);
                }
        }
    } else {
#pragma unroll
        for (int fn = 0; fn < 4; ++fn) {
            const int col = colb + fn * 16;
            float bias;
            float* ob;
            if (col < 1024) { bias = bx[col]; ob = out + col; }
            else { bias = by[col - 1024]; ob = out + 4194304 + (col - 1024); }
#pragma unroll
            for (int fm = 0; fm < 4; ++fm)
#pragma unroll
                for (int r = 0; r < 4; ++r) {
                    const int tk = rowb + fm * 16 + r;
                    ob[(size_t)tk * 1024] = acc[fm][fn][r] + bias;
                }
        }
    }
}

// ---------------- Flash attention v2: swapped QK^T, in-register softmax ----------------
// 512 blocks = 64 (b,h) x 8 q-blocks. 4 waves x 32 q-rows = 128 q-rows/block.
// S^T = mfma(K,Q) puts a full q-row slice in-lane: row reduce = in-lane + 2 shfl.
// P repacked to bf16 via v_cvt_pk and exchanged through a small swizzled LDS buffer
// (4x ds_write_b64 + 4x ds_read_b128 per wave-tile, conflict-light).
__global__ __launch_bounds__(256) void attn_kernel(const u16* __restrict__ Q,
                                                   const u16* __restrict__ Kg,
                                                   const u16* __restrict__ Vt,
                                                   u16* __restrict__ xo) {
    __shared__ __align__(16) u16 Ks[2][64 * 64];
    __shared__ __align__(16) u16 Vs[2][64 * 64];
    __shared__ __align__(16) u16 Ps[4][32 * 72];
    const int tid = threadIdx.x, lane = tid & 63, w = tid >> 6;
    const int bh = blockIdx.x >> 3, qblk = blockIdx.x & 7;
    const u16* Qh = Q + (size_t)bh * 65536;
    const u16* Kh = Kg + (size_t)bh * 65536;
    const u16* Vh = Vt + (size_t)bh * 65536;
    const int lr = lane & 15, cg = lane >> 4;
    const int q0 = qblk * 128 + w * 32;
    u16* Pw = &Ps[w][0];

    s16x8 qf[2][2];
#pragma unroll
    for (int qg = 0; qg < 2; ++qg)
#pragma unroll
        for (int ks = 0; ks < 2; ++ks)
            qf[qg][ks] =
                *(const s16x8*)(Qh + (size_t)(q0 + qg * 16 + lr) * 64 + ks * 32 + cg * 8);

    f32x4 o[2][4] = {};
    f32x4 l_o[2] = {};
    float m_s[2] = {-3e38f, -3e38f};
    int ba[4];
#pragma unroll
    for (int r = 0; r < 4; ++r) ba[r] = (cg * 4 + r) * 4;

#define STAGEKV(bufi, kv0)                                                               \
    do {                                                                                 \
        _Pragma("unroll") for (int i = 0; i < 2; ++i) {                                  \
            int idx = i * 256 + tid;                                                     \
            int row = idx >> 3, p = idx & 7;                                             \
            gload_lds16(Kh + (size_t)((kv0) + row) * 64 + ((p ^ (row & 7)) << 3),        \
                        &Ks[bufi][idx * 8]);                                             \
            gload_lds16(Vh + (size_t)row * 1024 + (kv0) + ((p ^ (row & 7)) << 3),        \
                        &Vs[bufi][idx * 8]);                                             \
        }                                                                                \
    } while (0)

    STAGEKV(0, 0);
    asm volatile("s_waitcnt vmcnt(0)" ::: "memory");
    __syncthreads();

    for (int t = 0; t < 16; ++t) {
        const int buf = t & 1;
        if (t < 15) STAGEKV(buf ^ 1, (t + 1) * 64);

        // ---- QK^T (swapped): s[qg][fn][r] = S[q = q0+qg*16+lr][k = fn*16+cg*4+r] ----
        f32x4 s[2][4] = {};
#pragma unroll
        for (int fn = 0; fn < 4; ++fn) {
            const int r = fn * 16 + lr;
#pragma unroll
            for (int ks = 0; ks < 2; ++ks) {
                const int c = cg + ks * 4;
                s16x8 kf = *(const s16x8*)&Ks[buf][r * 64 + ((c ^ (r & 7)) << 3)];
                s[0][fn] = mfma16(kf, qf[0][ks], s[0][fn]);
                s[1][fn] = mfma16(kf, qf[1][ks], s[1][fn]);
            }
        }

        // ---- online softmax, in-register (per q-row = lane lr, replicated over cg) ----
#pragma unroll
        for (int qg = 0; qg < 2; ++qg) {
            float tm = -3e38f;
#pragma unroll
            for (int fn = 0; fn < 4; ++fn)
#pragma unroll
                for (int r = 0; r < 4; ++r) tm = fmaxf(tm, s[qg][fn][r]);
            tm = fmaxf(tm, __shfl_xor(tm, 16));
            tm = fmaxf(tm, __shfl_xor(tm, 32));
            const float mn = fmaxf(m_s[qg], tm);
            const float corr = exp2a(m_s[qg] - mn);
            m_s[qg] = mn;
            float rs = 0.f;
            const int prow = (qg * 16 + lr) * 72;
#pragma unroll
            for (int fn = 0; fn < 4; ++fn) {
                const float p0 = exp2a(s[qg][fn][0] - mn);
                const float p1 = exp2a(s[qg][fn][1] - mn);
                const float p2 = exp2a(s[qg][fn][2] - mn);
                const float p3 = exp2a(s[qg][fn][3] - mn);
                rs += (p0 + p1) + (p2 + p3);
                uint2 dd;
                dd.x = cvtpk(p0, p1);
                dd.y = cvtpk(p2, p3);
                *(uint2*)(Pw + prow + (((2 * fn + (cg >> 1)) ^ (lr & 7)) << 3) +
                          ((cg & 1) << 2)) = dd;
            }
            rs += __shfl_xor(rs, 16);
            rs += __shfl_xor(rs, 32);
            // route max-correction & row-sum to the O-accumulator layout (q = cg*4+r)
            f32x4 corr_o, rs_o;
#pragma unroll
            for (int r = 0; r < 4; ++r) {
                corr_o[r] = __builtin_bit_cast(
                    float, __builtin_amdgcn_ds_bpermute(ba[r], __builtin_bit_cast(int, corr)));
                rs_o[r] = __builtin_bit_cast(
                    float, __builtin_amdgcn_ds_bpermute(ba[r], __builtin_bit_cast(int, rs)));
            }
            l_o[qg] = l_o[qg] * corr_o + rs_o;
#pragma unroll
            for (int fd = 0; fd < 4; ++fd) o[qg][fd] *= corr_o;
        }

        // ---- PV: read P fragments back (A-operand layout), multiply by V^T tiles ----
        s16x8 pf[2][2];
#pragma unroll
        for (int qg = 0; qg < 2; ++qg)
#pragma unroll
            for (int ks = 0; ks < 2; ++ks)
                pf[qg][ks] = *(const s16x8*)(Pw + (qg * 16 + lr) * 72 +
                                             (((4 * ks + cg) ^ (lr & 7)) << 3));
#pragma unroll
        for (int fd = 0; fd < 4; ++fd) {
            const int rr = fd * 16 + lr;
#pragma unroll
            for (int ks = 0; ks < 2; ++ks) {
                const int c = cg + ks * 4;
                s16x8 vf = *(const s16x8*)&Vs[buf][rr * 64 + ((c ^ (rr & 7)) << 3)];
                o[0][fd] = mfma16(pf[0][ks], vf, o[0][fd]);
                o[1][fd] = mfma16(pf[1][ks], vf, o[1][fd]);
            }
        }
        asm volatile("s_waitcnt vmcnt(0)" ::: "memory");
        __syncthreads();
    }
#undef STAGEKV

    const int b = bh >> 4, h = bh & 15;
#pragma unroll
    for (int qg = 0; qg < 2; ++qg) {
        f32x4 inv;
#pragma unroll
        for (int r = 0; r < 4; ++r) inv[r] = 1.0f / l_o[qg][r];
#pragma unroll
        for (int r = 0; r < 4; ++r) {
            const int qrow = q0 + qg * 16 + cg * 4 + r;
#pragma unroll
            for (int fd = 0; fd < 4; ++fd)
                xo[(size_t)(b * 1024 + qrow) * 1024 + h * 64 + fd * 16 + lr] =
                    f2bf(o[qg][fd][r] * inv[r]);
        }
    }
}

extern "C" void kernel_launch(void* const* d_in, const int* in_sizes, int n_in,
                              void* d_out, int out_size, void* d_ws, size_t ws_size,
                              hipStream_t stream) {
    const float* x = (const float*)d_in[0];
    const float* gx = (const float*)d_in[2];
    const float* bxv = (const float*)d_in[3];
    const float* Wqkv = (const float*)d_in[6];
    const float* Woutx = (const float*)d_in[8];
    const float* boutx = (const float*)d_in[9];
    const float* Wouty = (const float*)d_in[10];
    const float* bouty = (const float*)d_in[11];
    float* out = (float*)d_out;

    u16* ws = (u16*)d_ws;
    u16* xn = ws;                           // 4096*1024
    u16* wqkv_t = xn + 4096 * 1024;         // 3072*1024
    u16* wout_t = wqkv_t + 3072 * 1024;     // 2048*1024
    u16* Qb = wout_t + 2048 * 1024;         // 64*1024*64
    u16* Kb = Qb + 64 * 1024 * 64;
    u16* Vb = Kb + 64 * 1024 * 64;
    u16* Vtb = Vb + 64 * 1024 * 64;
    u16* xob = Vtb + 64 * 1024 * 64;        // 4096*1024

    ln_kernel<<<4096, 256, 0, stream>>>(x, gx, bxv, xn);
    transpose_w<<<dim3(48, 16), 256, 0, stream>>>(Wqkv, wqkv_t, 3072);
    transpose_w<<<dim3(16, 16), 256, 0, stream>>>(Woutx, wout_t, 1024);
    transpose_w<<<dim3(16, 16), 256, 0, stream>>>(Wouty, wout_t + 1024 * 1024, 1024);
    gemm_bt<0><<<dim3(24, 32), 256, 0, stream>>>(xn, wqkv_t, Qb, Kb, Vb, nullptr,
                                                 nullptr, nullptr, 1024);
    transpose_v<<<dim3(16, 64), 256, 0, stream>>>(Vb, Vtb);
    attn_kernel<<<512, 256, 0, stream>>>(Qb, Kb, Vtb, xob);
    gemm_bt<1><<<dim3(16, 32), 256, 0, stream>>>(xob, wout_t, nullptr, nullptr, nullptr,
                                                 boutx, bouty, out, 1024);
}

// Round 3
// 122.265 us; speedup vs baseline: 1.2434x; 1.1073x over previous
//
#include <hip/hip_runtime.h>

typedef __attribute__((ext_vector_type(8))) short s16x8;
typedef __attribute__((ext_vector_type(4))) float f32x4;
typedef unsigned short u16;

#define DEV __device__ __forceinline__

DEV u16 f2bf(float f) {
    unsigned u = __builtin_bit_cast(unsigned, f);
    unsigned r = u + 0x7fffu + ((u >> 16) & 1u);
    return (u16)(r >> 16);
}

DEV float exp2a(float x) {
    float r;
    asm("v_exp_f32 %0, %1" : "=v"(r) : "v"(x));
    return r;
}

DEV unsigned cvtpk(float lo, float hi) {
    unsigned r;
    asm("v_cvt_pk_bf16_f32 %0, %1, %2" : "=v"(r) : "v"(lo), "v"(hi));
    return r;
}

DEV void gload_lds16(const void* g, void* l) {
    __builtin_amdgcn_global_load_lds(
        (const __attribute__((address_space(1))) unsigned int*)g,
        (__attribute__((address_space(3))) unsigned int*)l, 16, 0, 0);
}

DEV f32x4 mfma16(s16x8 a, s16x8 b, f32x4 c) {
    return __builtin_amdgcn_mfma_f32_16x16x32_bf16(a, b, c, 0, 0, 0);
}

// ---------------- LayerNorm: f32 in -> bf16 out, one block per row ----------------
__global__ __launch_bounds__(256) void ln_kernel(const float* __restrict__ x,
                                                 const float* __restrict__ g,
                                                 const float* __restrict__ b,
                                                 u16* __restrict__ xn) {
    const int row = blockIdx.x, t = threadIdx.x;
    const float4 v = *(const float4*)(x + (size_t)row * 1024 + t * 4);
    float s1 = v.x + v.y + v.z + v.w;
    float s2 = v.x * v.x + v.y * v.y + v.z * v.z + v.w * v.w;
#pragma unroll
    for (int d = 1; d < 64; d <<= 1) {
        s1 += __shfl_xor(s1, d);
        s2 += __shfl_xor(s2, d);
    }
    __shared__ float red[8];
    if ((t & 63) == 0) { red[(t >> 6) * 2] = s1; red[(t >> 6) * 2 + 1] = s2; }
    __syncthreads();
    s1 = red[0] + red[2] + red[4] + red[6];
    s2 = red[1] + red[3] + red[5] + red[7];
    const float mu = s1 * (1.0f / 1024.0f);
    const float var = s2 * (1.0f / 1024.0f) - mu * mu;
    const float rs = rsqrtf(var + 1e-5f);
    const float4 gv = *(const float4*)(g + t * 4);
    const float4 bv = *(const float4*)(b + t * 4);
    ushort4 o;
    o.x = f2bf((v.x - mu) * rs * gv.x + bv.x);
    o.y = f2bf((v.y - mu) * rs * gv.y + bv.y);
    o.z = f2bf((v.z - mu) * rs * gv.z + bv.z);
    o.w = f2bf((v.w - mu) * rs * gv.w + bv.w);
    *(ushort4*)(xn + (size_t)row * 1024 + t * 4) = o;
}

// -------- Weight transpose + cast: src f32 [1024 K][ld N] -> dst bf16 [N][1024] --------
__global__ __launch_bounds__(256) void transpose_w(const float* __restrict__ src,
                                                   u16* __restrict__ dst, int ld) {
    __shared__ float tile[64][68];
    const int t = threadIdx.x;
    const int n0 = blockIdx.x * 64, k0 = blockIdx.y * 64;
    const int kl = t >> 4, nl = (t & 15) * 4;
#pragma unroll
    for (int p = 0; p < 4; ++p) {
        float4 v = *(const float4*)(src + (size_t)(k0 + kl + p * 16) * ld + n0 + nl);
        tile[kl + p * 16][nl + 0] = v.x;
        tile[kl + p * 16][nl + 1] = v.y;
        tile[kl + p * 16][nl + 2] = v.z;
        tile[kl + p * 16][nl + 3] = v.w;
    }
    __syncthreads();
    const int nl2 = t >> 2, kc = (t & 3) * 16;
    __align__(16) u16 tmp[16];
#pragma unroll
    for (int j = 0; j < 16; ++j) tmp[j] = f2bf(tile[kc + j][nl2]);
    u16* d = dst + (size_t)(n0 + nl2) * 1024 + k0 + kc;
    ((uint4*)d)[0] = ((const uint4*)tmp)[0];
    ((uint4*)d)[1] = ((const uint4*)tmp)[1];
}

// -------- V transpose (bf16): per (b,h) [1024 j][64 d] -> [64 d][1024 j] --------
__global__ __launch_bounds__(256) void transpose_v(const u16* __restrict__ V,
                                                   u16* __restrict__ Vt) {
    __shared__ u16 tile[64][72];
    const int t = threadIdx.x;
    const int j0 = blockIdx.x * 64;
    const int bh = blockIdx.y;
    const u16* src = V + (size_t)bh * 65536;
    const int jl = t >> 4, dl = (t & 15) * 4;
#pragma unroll
    for (int p = 0; p < 4; ++p) {
        ushort4 v = *(const ushort4*)(src + (size_t)(j0 + jl + p * 16) * 64 + dl);
        *(ushort4*)&tile[jl + p * 16][dl] = v;
    }
    __syncthreads();
    const int dl2 = t >> 2, jc = (t & 3) * 16;
    __align__(16) u16 tmp[16];
#pragma unroll
    for (int j = 0; j < 16; ++j) tmp[j] = tile[jc + j][dl2];
    u16* d = Vt + (size_t)bh * 65536 + (size_t)dl2 * 1024 + j0 + jc;
    ((uint4*)d)[0] = ((const uint4*)tmp)[0];
    ((uint4*)d)[1] = ((const uint4*)tmp)[1];
}

// ---------------- GEMM C = A @ B^T, A[M][K] bf16, B[N][K] bf16 (K-major) ----------------
// 128x128 tile, BK=32, 4 waves (2x2), 16x16x32 MFMA, global_load_lds + XOR swizzle.
// EPI==0: scatter q/k/v (q scaled by SCALE*log2e). EPI==1: dual output + bias, f32.
template <int EPI>
__global__ __launch_bounds__(256) void gemm_bt(const u16* __restrict__ A,
                                               const u16* __restrict__ B,
                                               u16* __restrict__ Qb, u16* __restrict__ Kb,
                                               u16* __restrict__ Vb,
                                               const float* __restrict__ bx,
                                               const float* __restrict__ by,
                                               float* __restrict__ out, int K) {
    __shared__ __align__(16) u16 As[2][128 * 32];
    __shared__ __align__(16) u16 Bs[2][128 * 32];
    const int tid = threadIdx.x, lane = tid & 63;
    const int wave = tid >> 6, wm = wave >> 1, wn = wave & 1;
    const int m0 = blockIdx.y * 128, n0 = blockIdx.x * 128;
    const int lr = lane & 15, cg = lane >> 4;
    f32x4 acc[4][4] = {};

#define STAGE(bufi, k0)                                                            \
    do {                                                                           \
        _Pragma("unroll") for (int i = 0; i < 2; ++i) {                            \
            int idx = i * 256 + tid;                                               \
            int row = idx >> 2, p = idx & 3;                                       \
            int kk = (k0) + ((p ^ ((row >> 1) & 3)) << 3);                         \
            gload_lds16(A + (size_t)(m0 + row) * K + kk, &As[bufi][idx * 8]);      \
            gload_lds16(B + (size_t)(n0 + row) * K + kk, &Bs[bufi][idx * 8]);      \
        }                                                                          \
    } while (0)

    STAGE(0, 0);
    asm volatile("s_waitcnt vmcnt(0)" ::: "memory");
    __syncthreads();
    const int nk = K >> 5;
    for (int t = 0; t < nk; ++t) {
        const int buf = t & 1;
        if (t + 1 < nk) STAGE(buf ^ 1, (t + 1) << 5);
        s16x8 a[4], b[4];
#pragma unroll
        for (int f = 0; f < 4; ++f) {
            int r = wm * 64 + f * 16 + lr;
            a[f] = *(const s16x8*)&As[buf][r * 32 + ((cg ^ ((r >> 1) & 3)) << 3)];
            int r2 = wn * 64 + f * 16 + lr;
            b[f] = *(const s16x8*)&Bs[buf][r2 * 32 + ((cg ^ ((r2 >> 1) & 3)) << 3)];
        }
#pragma unroll
        for (int fm = 0; fm < 4; ++fm)
#pragma unroll
            for (int fn = 0; fn < 4; ++fn) acc[fm][fn] = mfma16(a[fm], b[fn], acc[fm][fn]);
        asm volatile("s_waitcnt vmcnt(0)" ::: "memory");
        __syncthreads();
    }
#undef STAGE

    const int colb = n0 + wn * 64 + lr;
    const int rowb = m0 + wm * 64 + cg * 4;
    if (EPI == 0) {
#pragma unroll
        for (int fn = 0; fn < 4; ++fn) {
            const int col = colb + fn * 16;
            const int which = col >> 10, hd = col & 1023;
            const int h = hd >> 6, dd = hd & 63;
            u16* dst = (which == 0) ? Qb : (which == 1) ? Kb : Vb;
            // Q pre-scaled by SCALE*log2(e) so softmax can use raw v_exp_f32 (exp2)
            const float sc = (which == 0) ? 0.18033688011112042f : 1.0f;
#pragma unroll
            for (int fm = 0; fm < 4; ++fm)
#pragma unroll
                for (int r = 0; r < 4; ++r) {
                    const int tk = rowb + fm * 16 + r;
                    const int bb = tk >> 10, ii = tk & 1023;
                    dst[(size_t)(((bb << 4) + h) * 1024 + ii) * 64 + dd] =
                        f2bf(acc[fm][fn][r] * sc);
                }
        }
    } else {
#pragma unroll
        for (int fn = 0; fn < 4; ++fn) {
            const int col = colb + fn * 16;
            float bias;
            float* ob;
            if (col < 1024) { bias = bx[col]; ob = out + col; }
            else { bias = by[col - 1024]; ob = out + 4194304 + (col - 1024); }
#pragma unroll
            for (int fm = 0; fm < 4; ++fm)
#pragma unroll
                for (int r = 0; r < 4; ++r) {
                    const int tk = rowb + fm * 16 + r;
                    ob[(size_t)tk * 1024] = acc[fm][fn][r] + bias;
                }
        }
    }
}

// ---------------- Flash attention v3: swapped QK^T, in-register softmax ----------------
// 512 blocks = 64 (b,h) x 8 q-blocks. 4 waves x 32 q-rows = 128 q-rows/block.
// S^T = mfma(K,Q): lane holds full q-row slice -> row reduce = in-lane + 2 shfl.
// P via [32][64] stride-64 XOR-swizzled per-wave LDS (conflict-free by bank enum).
// Running sum l kept in S-layout (routed once at end); defer-max (THR=8 in exp2
// units) makes the o-rescale + corr routing rare.
__global__ __launch_bounds__(256) void attn_kernel(const u16* __restrict__ Q,
                                                   const u16* __restrict__ Kg,
                                                   const u16* __restrict__ Vt,
                                                   u16* __restrict__ xo) {
    __shared__ __align__(16) u16 Ks[2][64 * 64];
    __shared__ __align__(16) u16 Vs[2][64 * 64];
    __shared__ __align__(16) u16 Ps[4][32 * 64];
    const int tid = threadIdx.x, lane = tid & 63, w = tid >> 6;
    const int bh = blockIdx.x >> 3, qblk = blockIdx.x & 7;
    const u16* Qh = Q + (size_t)bh * 65536;
    const u16* Kh = Kg + (size_t)bh * 65536;
    const u16* Vh = Vt + (size_t)bh * 65536;
    const int lr = lane & 15, cg = lane >> 4;
    const int q0 = qblk * 128 + w * 32;
    u16* Pw = &Ps[w][0];

    s16x8 qf[2][2];
#pragma unroll
    for (int qg = 0; qg < 2; ++qg)
#pragma unroll
        for (int ks = 0; ks < 2; ++ks)
            qf[qg][ks] =
                *(const s16x8*)(Qh + (size_t)(q0 + qg * 16 + lr) * 64 + ks * 32 + cg * 8);

    f32x4 o[2][4] = {};
    float l_s[2] = {0.f, 0.f};
    float m_s[2] = {-3e38f, -3e38f};
    int ba[4];
#pragma unroll
    for (int r = 0; r < 4; ++r) ba[r] = (cg * 4 + r) * 4;

#define STAGEKV(bufi, kv0)                                                               \
    do {                                                                                 \
        _Pragma("unroll") for (int i = 0; i < 2; ++i) {                                  \
            int idx = i * 256 + tid;                                                     \
            int row = idx >> 3, p = idx & 7;                                             \
            gload_lds16(Kh + (size_t)((kv0) + row) * 64 + ((p ^ (row & 7)) << 3),        \
                        &Ks[bufi][idx * 8]);                                             \
            gload_lds16(Vh + (size_t)row * 1024 + (kv0) + ((p ^ (row & 7)) << 3),        \
                        &Vs[bufi][idx * 8]);                                             \
        }                                                                                \
    } while (0)

    STAGEKV(0, 0);
    asm volatile("s_waitcnt vmcnt(0)" ::: "memory");
    __syncthreads();

    for (int t = 0; t < 16; ++t) {
        const int buf = t & 1;
        if (t < 15) STAGEKV(buf ^ 1, (t + 1) * 64);

        // ---- QK^T (swapped): s[qg][fn][r] = S[q = q0+qg*16+lr][k = fn*16+cg*4+r] ----
        f32x4 s[2][4] = {};
#pragma unroll
        for (int fn = 0; fn < 4; ++fn) {
            const int r = fn * 16 + lr;
#pragma unroll
            for (int ks = 0; ks < 2; ++ks) {
                const int c = cg + ks * 4;
                s16x8 kf = *(const s16x8*)&Ks[buf][r * 64 + ((c ^ (r & 7)) << 3)];
                s[0][fn] = mfma16(kf, qf[0][ks], s[0][fn]);
                s[1][fn] = mfma16(kf, qf[1][ks], s[1][fn]);
            }
        }

        // ---- online softmax, in-register (q-row = lane lr, replicated over cg) ----
#pragma unroll
        for (int qg = 0; qg < 2; ++qg) {
            float tm = -3e38f;
#pragma unroll
            for (int fn = 0; fn < 4; ++fn)
#pragma unroll
                for (int r = 0; r < 4; ++r) tm = fmaxf(tm, s[qg][fn][r]);
            tm = fmaxf(tm, __shfl_xor(tm, 16));
            tm = fmaxf(tm, __shfl_xor(tm, 32));
            // defer-max: only rescale when some row's max grew past THR=8 (exp2 units)
            if (!__all(tm <= m_s[qg] + 8.0f)) {
                const float mn = fmaxf(m_s[qg], tm);
                const float corr = exp2a(m_s[qg] - mn);
                m_s[qg] = mn;
                l_s[qg] *= corr;
                f32x4 corr_o;
#pragma unroll
                for (int r = 0; r < 4; ++r)
                    corr_o[r] = __builtin_bit_cast(
                        float,
                        __builtin_amdgcn_ds_bpermute(ba[r], __builtin_bit_cast(int, corr)));
#pragma unroll
                for (int fd = 0; fd < 4; ++fd) o[qg][fd] *= corr_o;
            }
            const float mn = m_s[qg];
            float rs = 0.f;
            const int prow = (qg * 16 + lr) * 64;
#pragma unroll
            for (int fn = 0; fn < 4; ++fn) {
                const float p0 = exp2a(s[qg][fn][0] - mn);
                const float p1 = exp2a(s[qg][fn][1] - mn);
                const float p2 = exp2a(s[qg][fn][2] - mn);
                const float p3 = exp2a(s[qg][fn][3] - mn);
                rs += (p0 + p1) + (p2 + p3);
                uint2 dd;
                dd.x = cvtpk(p0, p1);
                dd.y = cvtpk(p2, p3);
                *(uint2*)(Pw + prow + (((2 * fn + (cg >> 1)) ^ (lr & 7)) << 3) +
                          ((cg & 1) << 2)) = dd;
            }
            rs += __shfl_xor(rs, 16);
            rs += __shfl_xor(rs, 32);
            l_s[qg] += rs;
        }

        // ---- PV: read P fragments back (A-operand layout), multiply by V^T tiles ----
        s16x8 pf[2][2];
#pragma unroll
        for (int qg = 0; qg < 2; ++qg)
#pragma unroll
            for (int ks = 0; ks < 2; ++ks)
                pf[qg][ks] = *(const s16x8*)(Pw + (qg * 16 + lr) * 64 +
                                             (((4 * ks + cg) ^ (lr & 7)) << 3));
#pragma unroll
        for (int fd = 0; fd < 4; ++fd) {
            const int rr = fd * 16 + lr;
#pragma unroll
            for (int ks = 0; ks < 2; ++ks) {
                const int c = cg + ks * 4;
                s16x8 vf = *(const s16x8*)&Vs[buf][rr * 64 + ((c ^ (rr & 7)) << 3)];
                o[0][fd] = mfma16(pf[0][ks], vf, o[0][fd]);
                o[1][fd] = mfma16(pf[1][ks], vf, o[1][fd]);
            }
        }
        asm volatile("s_waitcnt vmcnt(0)" ::: "memory");
        __syncthreads();
    }
#undef STAGEKV

    const int b = bh >> 4, h = bh & 15;
#pragma unroll
    for (int qg = 0; qg < 2; ++qg) {
        f32x4 inv;
#pragma unroll
        for (int r = 0; r < 4; ++r) {
            const float lq = __builtin_bit_cast(
                float, __builtin_amdgcn_ds_bpermute(ba[r], __builtin_bit_cast(int, l_s[qg])));
            inv[r] = 1.0f / lq;
        }
#pragma unroll
        for (int r = 0; r < 4; ++r) {
            const int qrow = q0 + qg * 16 + cg * 4 + r;
#pragma unroll
            for (int fd = 0; fd < 4; ++fd)
                xo[(size_t)(b * 1024 + qrow) * 1024 + h * 64 + fd * 16 + lr] =
                    f2bf(o[qg][fd][r] * inv[r]);
        }
    }
}

extern "C" void kernel_launch(void* const* d_in, const int* in_sizes, int n_in,
                              void* d_out, int out_size, void* d_ws, size_t ws_size,
                              hipStream_t stream) {
    const float* x = (const float*)d_in[0];
    const float* gx = (const float*)d_in[2];
    const float* bxv = (const float*)d_in[3];
    const float* Wqkv = (const float*)d_in[6];
    const float* Woutx = (const float*)d_in[8];
    const float* boutx = (const float*)d_in[9];
    const float* Wouty = (const float*)d_in[10];
    const float* bouty = (const float*)d_in[11];
    float* out = (float*)d_out;

    u16* ws = (u16*)d_ws;
    u16* xn = ws;                           // 4096*1024
    u16* wqkv_t = xn + 4096 * 1024;         // 3072*1024
    u16* wout_t = wqkv_t + 3072 * 1024;     // 2048*1024
    u16* Qb = wout_t + 2048 * 1024;         // 64*1024*64
    u16* Kb = Qb + 64 * 1024 * 64;
    u16* Vb = Kb + 64 * 1024 * 64;
    u16* Vtb = Vb + 64 * 1024 * 64;
    u16* xob = Vtb + 64 * 1024 * 64;        // 4096*1024

    ln_kernel<<<4096, 256, 0, stream>>>(x, gx, bxv, xn);
    transpose_w<<<dim3(48, 16), 256, 0, stream>>>(Wqkv, wqkv_t, 3072);
    transpose_w<<<dim3(16, 16), 256, 0, stream>>>(Woutx, wout_t, 1024);
    transpose_w<<<dim3(16, 16), 256, 0, stream>>>(Wouty, wout_t + 1024 * 1024, 1024);
    gemm_bt<0><<<dim3(24, 32), 256, 0, stream>>>(xn, wqkv_t, Qb, Kb, Vb, nullptr,
                                                 nullptr, nullptr, 1024);
    transpose_v<<<dim3(16, 64), 256, 0, stream>>>(Vb, Vtb);
    attn_kernel<<<512, 256, 0, stream>>>(Qb, Kb, Vtb, xob);
    gemm_bt<1><<<dim3(16, 32), 256, 0, stream>>>(xob, wout_t, nullptr, nullptr, nullptr,
                                                 boutx, bouty, out, 1024);
}